// Round 4
// baseline (84.225 us; speedup 1.0000x reference)
//
#include <hip/hip_runtime.h>

// GraphPool: out[s,a,f] = max over {self, valid neighbors} atoms[s,idx,f],
// zeroed when atom has no valid neighbors. S=512, A=128, F=128, D=6.
//
// Block = (s, feature-half); internally software-pipelines its two
// feature-quarter units: async-stage slab0 -> [reg-prefetch slab1 || gather0
// + write0] -> ds_write slab1 -> gather1 + write1. Edge meta computed once
// per block. 36 KB LDS -> 4 blocks/CU.

constexpr int S  = 512;
constexpr int A  = 128;
constexpr int F  = 128;
constexpr int D  = 6;
constexpr int QF = 32;              // features per unit
constexpr int ROWB = QF * 4;        // LDS row bytes = 128
constexpr int SLOT = A * QF;        // floats per slab = 4096

#define GLOBAL_AS __attribute__((address_space(1)))
#define LDS_AS    __attribute__((address_space(3)))

__device__ __forceinline__ void gather_unit(const float* __restrict__ sl_slab,
                                            const int*   __restrict__ se,
                                            float* __restrict__ outb,
                                            int tid)
{
    const int q    = tid & 7;
    const int qoff = q * 16;
    const char* lbase = (const char*)sl_slab;

#pragma unroll
    for (int p = 0; p < 4; ++p) {
        const int a = p * 32 + (tid >> 3);

        const int4 e0 = *(const int4*)&se[a * 8];
        const int4 e1 = *(const int4*)&se[a * 8 + 4];
        const float maskf = __int_as_float(e1.z);

        float4 m = *(const float4*)(lbase + a * ROWB + qoff);  // self
        float4 v;
        v = *(const float4*)(lbase + e0.x + qoff);
        m.x = fmaxf(m.x, v.x); m.y = fmaxf(m.y, v.y);
        m.z = fmaxf(m.z, v.z); m.w = fmaxf(m.w, v.w);
        v = *(const float4*)(lbase + e0.y + qoff);
        m.x = fmaxf(m.x, v.x); m.y = fmaxf(m.y, v.y);
        m.z = fmaxf(m.z, v.z); m.w = fmaxf(m.w, v.w);
        v = *(const float4*)(lbase + e0.z + qoff);
        m.x = fmaxf(m.x, v.x); m.y = fmaxf(m.y, v.y);
        m.z = fmaxf(m.z, v.z); m.w = fmaxf(m.w, v.w);
        v = *(const float4*)(lbase + e0.w + qoff);
        m.x = fmaxf(m.x, v.x); m.y = fmaxf(m.y, v.y);
        m.z = fmaxf(m.z, v.z); m.w = fmaxf(m.w, v.w);
        v = *(const float4*)(lbase + e1.x + qoff);
        m.x = fmaxf(m.x, v.x); m.y = fmaxf(m.y, v.y);
        m.z = fmaxf(m.z, v.z); m.w = fmaxf(m.w, v.w);
        v = *(const float4*)(lbase + e1.y + qoff);
        m.x = fmaxf(m.x, v.x); m.y = fmaxf(m.y, v.y);
        m.z = fmaxf(m.z, v.z); m.w = fmaxf(m.w, v.w);

        m.x *= maskf; m.y *= maskf; m.z *= maskf; m.w *= maskf;

        *(float4*)(outb + (size_t)a * F) = m;
    }
}

__global__ __launch_bounds__(256, 4) void graphpool_kernel(
    const float* __restrict__ atoms,   // (S, A, F)
    const int*   __restrict__ edges,   // (S, A, D), -1 = padding
    float*       __restrict__ out)     // (S, A, F)
{
    __shared__ __align__(16) float sl[2 * SLOT];  // 32 KB: slab0, slab1
    __shared__ __align__(16) int   se[A * 8];     // 4 KB edge meta

    const int tid  = threadIdx.x;
    const int h    = blockIdx.x & 1;              // feature half
    const int s    = blockIdx.x >> 1;
    const int wave = tid >> 6;
    const int lane = tid & 63;

    const float* slab0 = atoms + (size_t)s * (A * F) + (h * 2) * QF;
    const float* slab1 = slab0 + QF;

    // ---- Phase A: async stage slab0 (16 chunks x 1 KB) ----
    {
        const int rowq = lane >> 3;
        const int colq = lane & 7;
#pragma unroll
        for (int i = 0; i < 4; ++i) {
            const int chunk = wave * 4 + i;
            const float* gp = slab0 + (size_t)(chunk * 8 + rowq) * F + colq * 4;
            float* lp = &sl[chunk * 256];         // wave-uniform base
            __builtin_amdgcn_global_load_lds((const GLOBAL_AS float*)gp,
                                             (LDS_AS float*)lp, 16, 0, 0);
        }
    }
    // ---- edge meta: thread t < 128 handles atom t, once per block ----
    if (tid < A) {
        const int* eg = edges + ((size_t)s * A + tid) * D;
        const int i0 = eg[0], i1 = eg[1], i2 = eg[2];
        const int i3 = eg[3], i4 = eg[4], i5 = eg[5];
        const int deg = (i0 >= 0) + (i1 >= 0) + (i2 >= 0) +
                        (i3 >= 0) + (i4 >= 0) + (i5 >= 0);
        const int self = tid * ROWB;
        int4 w0, w1;
        w0.x = (i0 >= 0) ? i0 * ROWB : self;
        w0.y = (i1 >= 0) ? i1 * ROWB : self;
        w0.z = (i2 >= 0) ? i2 * ROWB : self;
        w0.w = (i3 >= 0) ? i3 * ROWB : self;
        w1.x = (i4 >= 0) ? i4 * ROWB : self;
        w1.y = (i5 >= 0) ? i5 * ROWB : self;
        w1.z = __float_as_int(deg ? 1.0f : 0.0f);
        w1.w = 0;
        *(int4*)&se[tid * 8]     = w0;
        *(int4*)&se[tid * 8 + 4] = w1;
    }

    __syncthreads();   // slab0 + meta visible

    // ---- Phase B: prefetch slab1 into regs (vmcnt loads fly over gather0) ----
    const int prow = tid >> 3;        // base row for slot tid
    const int pcol = (tid & 7) * 4;
    float4 r0 = *(const float4*)(slab1 + (size_t)(prow +  0) * F + pcol);
    float4 r1 = *(const float4*)(slab1 + (size_t)(prow + 32) * F + pcol);
    float4 r2 = *(const float4*)(slab1 + (size_t)(prow + 64) * F + pcol);
    float4 r3 = *(const float4*)(slab1 + (size_t)(prow + 96) * F + pcol);

    // gather + write unit0
    float* outb0 = out + (size_t)s * (A * F) + (h * 2) * QF + (tid & 7) * 4;
    gather_unit(sl, se, outb0, tid);

    // commit slab1 to LDS
    *(float4*)(&sl[SLOT + (tid +   0) * 4]) = r0;
    *(float4*)(&sl[SLOT + (tid + 256) * 4]) = r1;
    *(float4*)(&sl[SLOT + (tid + 512) * 4]) = r2;
    *(float4*)(&sl[SLOT + (tid + 768) * 4]) = r3;

    __syncthreads();   // slab1 visible

    // ---- Phase C: gather + write unit1 ----
    float* outb1 = outb0 + QF;
    gather_unit(sl + SLOT, se, outb1, tid);
}

extern "C" void kernel_launch(void* const* d_in, const int* in_sizes, int n_in,
                              void* d_out, int out_size, void* d_ws, size_t ws_size,
                              hipStream_t stream) {
    const float* atoms = (const float*)d_in[0];
    const int*   edges = (const int*)d_in[1];
    float*       out   = (float*)d_out;

    graphpool_kernel<<<S * 2, 256, 0, stream>>>(atoms, edges, out);
}